// Round 4
// baseline (115.878 us; speedup 1.0000x reference)
//
#include <hip/hip_runtime.h>
#include <hip/hip_bf16.h>

// out[b,t,u,c] = enc[b,t,:]·W[c,:512] + dec[b,u,:]·W[c,512:]
// B=4, T=256, U=64, D=512, C=1024. Output 256 MiB fp32 (write floor ~39us).
//
// K1 cvt:   fp32 -> bf16 for enc/dec/W.
// K2 fused: per block (16 bt-rows x 128 c-cols): MFMA enc tile + dec tile
//           into LDS, then stream out[bt,u,c] = encS + decS with nontemporal
//           float4 stores. GEMM work hides under the write-bound stream.

typedef float v4f   __attribute__((ext_vector_type(4)));
typedef float f32x4 __attribute__((ext_vector_type(4)));
typedef __attribute__((ext_vector_type(8))) short short8;
typedef __attribute__((ext_vector_type(4))) short short4v;

__device__ inline short bf16_of(float f) {
    __hip_bfloat16 h = __float2bfloat16(f);   // RNE
    return *reinterpret_cast<short*>(&h);
}

// ---------------- K1: fp32 -> bf16 conversion --------------------------------
// float4 units: enc 131072, dec 32768, W 262144  (total 425984; grid 1664).
__global__ __launch_bounds__(256) void cvt_fp32_bf16(
    const float* __restrict__ enc, const float* __restrict__ dec,
    const float* __restrict__ W,
    ushort* __restrict__ enc_bf, ushort* __restrict__ dec_bf,
    ushort* __restrict__ W_bf)
{
    const int N1 = 131072, N2 = 32768;
    int i = blockIdx.x * 256 + threadIdx.x;
    const float* src; ushort* dst; int j;
    if (i < N1)           { src = enc; dst = enc_bf; j = i; }
    else if (i < N1 + N2) { src = dec; dst = dec_bf; j = i - N1; }
    else                  { src = W;   dst = W_bf;   j = i - N1 - N2; }
    float4 v = *(const float4*)&src[(size_t)j * 4];
    short4v o;
    o[0] = bf16_of(v.x); o[1] = bf16_of(v.y);
    o[2] = bf16_of(v.z); o[3] = bf16_of(v.w);
    *(short4v*)&dst[(size_t)j * 4] = o;
}

// ---------------- K2: fused projections + broadcast-add stream ---------------
// Grid (64 bt-tiles, 8 c-tiles), 256 threads = 4 waves.
// Wave w owns c columns [w*32, w*32+32) of the 128-wide tile.
__global__ __launch_bounds__(256) void fused_proj_add(
    const ushort* __restrict__ Xe,  // (1024, 512) bf16
    const ushort* __restrict__ Xd,  // (256, 512)  bf16
    const ushort* __restrict__ W,   // (1024, 1024) bf16; enc cols [0,512), dec [512,1024)
    float* __restrict__ out)        // (1024, 64, 1024)
{
    const int tid  = threadIdx.x;
    const int wave = tid >> 6;
    const int lane = tid & 63;
    const int l16  = lane & 15;
    const int kq   = lane >> 4;          // 0..3

    const int btBase = blockIdx.x * 16;  // 0..1008
    const int cBase  = blockIdx.y * 128;
    const int b      = blockIdx.x >> 4;  // 16 bt-tiles per batch
    const int wc     = wave * 32;

    __shared__ float encS[16][128];      // 8 KiB
    __shared__ float decS[64][128];      // 32 KiB

    // ---- Phase 1: enc tile (16 x 128), K=512 ----
    {
        const ushort* ar  = Xe + (size_t)(btBase + l16) * 512;
        const ushort* br0 = W  + (size_t)(cBase + wc + l16) * 1024;   // enc half
        const ushort* br1 = br0 + (size_t)16 * 1024;
        f32x4 e0 = {0.f,0.f,0.f,0.f}, e1 = {0.f,0.f,0.f,0.f};
#pragma unroll 4
        for (int kb = 0; kb < 512; kb += 32) {
            const int k = kb + kq * 8;
            short8 a  = *(const short8*)&ar[k];
            short8 b0 = *(const short8*)&br0[k];
            short8 b1 = *(const short8*)&br1[k];
            e0 = __builtin_amdgcn_mfma_f32_16x16x32_bf16(a, b0, e0, 0, 0, 0);
            e1 = __builtin_amdgcn_mfma_f32_16x16x32_bf16(a, b1, e1, 0, 0, 0);
        }
#pragma unroll
        for (int r = 0; r < 4; ++r) {            // D: col=l16, row=kq*4+r
            encS[kq * 4 + r][wc + l16]      = e0[r];
            encS[kq * 4 + r][wc + 16 + l16] = e1[r];
        }
    }

    // ---- Phase 2: dec tile (64 x 128), K=512 ----
    {
        const ushort* dr  = Xd + (size_t)(b * 64 + l16) * 512;        // +uf*16 rows
        const ushort* wr0 = W  + (size_t)(cBase + wc + l16) * 1024 + 512;  // dec half
        const ushort* wr1 = wr0 + (size_t)16 * 1024;
        f32x4 d0[4] = {{0.f,0.f,0.f,0.f},{0.f,0.f,0.f,0.f},{0.f,0.f,0.f,0.f},{0.f,0.f,0.f,0.f}};
        f32x4 d1[4] = {{0.f,0.f,0.f,0.f},{0.f,0.f,0.f,0.f},{0.f,0.f,0.f,0.f},{0.f,0.f,0.f,0.f}};
#pragma unroll 2
        for (int kb = 0; kb < 512; kb += 32) {
            const int k = kb + kq * 8;
            short8 b0 = *(const short8*)&wr0[k];
            short8 b1 = *(const short8*)&wr1[k];
#pragma unroll
            for (int uf = 0; uf < 4; ++uf) {
                short8 a = *(const short8*)&dr[(size_t)uf * 16 * 512 + k];
                d0[uf] = __builtin_amdgcn_mfma_f32_16x16x32_bf16(a, b0, d0[uf], 0, 0, 0);
                d1[uf] = __builtin_amdgcn_mfma_f32_16x16x32_bf16(a, b1, d1[uf], 0, 0, 0);
            }
        }
#pragma unroll
        for (int uf = 0; uf < 4; ++uf)
#pragma unroll
            for (int r = 0; r < 4; ++r) {
                decS[uf * 16 + kq * 4 + r][wc + l16]      = d0[uf][r];
                decS[uf * 16 + kq * 4 + r][wc + 16 + l16] = d1[uf][r];
            }
    }

    __syncthreads();

    // ---- Phase 3: stream 16x64x128 output chunk (512 KiB) ----
    const int lane5 = tid & 31;          // c float4 slot
    const int g     = tid >> 5;          // 0..7 bt group
    const int c4    = lane5 * 4;

    const float4 ea = *(const float4*)&encS[g][c4];
    const float4 eb = *(const float4*)&encS[g + 8][c4];

    float* poa = out + ((size_t)(btBase + g)     * 64) * 1024 + cBase + c4;
    float* pob = out + ((size_t)(btBase + g + 8) * 64) * 1024 + cBase + c4;

#pragma unroll 8
    for (int u = 0; u < 64; ++u) {
        float4 d = *(const float4*)&decS[u][c4];
        v4f ra = {ea.x + d.x, ea.y + d.y, ea.z + d.z, ea.w + d.w};
        v4f rb = {eb.x + d.x, eb.y + d.y, eb.z + d.z, eb.w + d.w};
        __builtin_nontemporal_store(ra, (v4f*)&poa[(size_t)u * 1024]);
        __builtin_nontemporal_store(rb, (v4f*)&pob[(size_t)u * 1024]);
    }
}

extern "C" void kernel_launch(void* const* d_in, const int* in_sizes, int n_in,
                              void* d_out, int out_size, void* d_ws, size_t ws_size,
                              hipStream_t stream) {
    const float* enc = (const float*)d_in[0];   // (4,256,512)
    const float* dec = (const float*)d_in[1];   // (4,64,512)
    const float* W   = (const float*)d_in[2];   // (1024,1024)
    float* out = (float*)d_out;

    // Workspace: enc_bf 1 MiB | dec_bf 256 KiB | W_bf 2 MiB  (= 3.25 MiB)
    char* ws = (char*)d_ws;
    ushort* enc_bf = (ushort*)(ws);
    ushort* dec_bf = (ushort*)(ws + (1u << 20));
    ushort* W_bf   = (ushort*)(ws + (1u << 20) + (1u << 18));

    cvt_fp32_bf16<<<dim3(1664), 256, 0, stream>>>(enc, dec, W, enc_bf, dec_bf, W_bf);
    fused_proj_add<<<dim3(64, 8), 256, 0, stream>>>(enc_bf, dec_bf, W_bf, out);
}

// Round 5
// 74.600 us; speedup vs baseline: 1.5533x; 1.5533x over previous
//
#include <hip/hip_runtime.h>
#include <hip/hip_bf16.h>

// out[b,t,u,c] = enc[b,t,:]·W[c,:512] + dec[b,u,:]·W[c,512:]
// B=4, T=256, U=64, D=512, C=1024. Output 256 MiB fp32 (write floor ~40us).
//
// K1 cvt:  fp32 -> bf16 (enc/dec/W) once.
// K2 gemm: bf16-MFMA projections, direct global->reg fragments, no staging.
//          Split-K in block: 4 waves = {k-half 0/1} x {c-half 0/1}; kz=1
//          partials through LDS (stride 65, conflict-free). 1280 blocks
//          (~5 waves/SIMD) to hide L2 latency; 8 k-steps per wave.
// K3 add:  broadcast-add streaming the output with nontemporal float4.

typedef float v4f   __attribute__((ext_vector_type(4)));
typedef float f32x4 __attribute__((ext_vector_type(4)));
typedef __attribute__((ext_vector_type(8))) short short8;
typedef __attribute__((ext_vector_type(4))) short short4v;

__device__ inline short bf16_of(float f) {
    __hip_bfloat16 h = __float2bfloat16(f);   // RNE
    return *reinterpret_cast<short*>(&h);
}

// ---------------- K1: fp32 -> bf16 conversion --------------------------------
// float4 units: enc 131072, dec 32768, W 262144  (total 425984; grid 1664).
__global__ __launch_bounds__(256) void cvt_fp32_bf16(
    const float* __restrict__ enc, const float* __restrict__ dec,
    const float* __restrict__ W,
    ushort* __restrict__ enc_bf, ushort* __restrict__ dec_bf,
    ushort* __restrict__ W_bf)
{
    const int N1 = 131072, N2 = 32768;
    int i = blockIdx.x * 256 + threadIdx.x;
    const float* src; ushort* dst; int j;
    if (i < N1)           { src = enc; dst = enc_bf; j = i; }
    else if (i < N1 + N2) { src = dec; dst = dec_bf; j = i - N1; }
    else                  { src = W;   dst = W_bf;   j = i - N1 - N2; }
    float4 v = *(const float4*)&src[(size_t)j * 4];
    short4v o;
    o[0] = bf16_of(v.x); o[1] = bf16_of(v.y);
    o[2] = bf16_of(v.z); o[3] = bf16_of(v.w);
    *(short4v*)&dst[(size_t)j * 4] = o;
}

// ---------------- K2: bf16 MFMA projection GEMM, in-block split-K ------------
// Grid (16 c-tiles, 80 m-tiles[64 enc + 16 dec]); block tile = 16(m) x 64(c).
// Wave w: kz = w>>1 (K half), wn = (w&1)*32 (c half). 2 MFMA per k-step.
__global__ __launch_bounds__(256, 4) void proj_gemm_bf16(
    const ushort* __restrict__ Xe,  // (1024, 512) bf16
    const ushort* __restrict__ Xd,  // (256, 512)  bf16
    const ushort* __restrict__ W,   // (1024, 1024) bf16; enc cols [0,512), dec [512,1024)
    float* __restrict__ Pe,         // (1024, 1024)
    float* __restrict__ Pd)         // (256, 1024)
{
    const int tid  = threadIdx.x;
    const int wave = tid >> 6;
    const int lane = tid & 63;
    const int l16  = lane & 15;
    const int kq   = lane >> 4;          // 0..3

    const int kz = wave >> 1;            // K half: [kz*256, kz*256+256)
    const int wn = (wave & 1) * 32;      // c half of the 64-wide tile

    const ushort* X; float* P; int wofs, mBase;
    if (blockIdx.y < 64) { X = Xe; P = Pe; wofs = 0;   mBase = blockIdx.y * 16; }
    else                 { X = Xd; P = Pd; wofs = 512; mBase = (blockIdx.y - 64) * 16; }
    const int cBase = blockIdx.x * 64;

    const ushort* xr  = X + (size_t)(mBase + l16) * 512 + kz * 256;
    const ushort* wr0 = W + (size_t)(cBase + wn + l16) * 1024 + wofs + kz * 256;
    const ushort* wr1 = wr0 + (size_t)16 * 1024;

    f32x4 acc0 = {0.f, 0.f, 0.f, 0.f};
    f32x4 acc1 = {0.f, 0.f, 0.f, 0.f};

#pragma unroll 4
    for (int kb = 0; kb < 256; kb += 32) {
        const int k = kb + kq * 8;
        short8 a  = *(const short8*)&xr[k];
        short8 b0 = *(const short8*)&wr0[k];
        short8 b1 = *(const short8*)&wr1[k];
        acc0 = __builtin_amdgcn_mfma_f32_16x16x32_bf16(a, b0, acc0, 0, 0, 0);
        acc1 = __builtin_amdgcn_mfma_f32_16x16x32_bf16(a, b1, acc1, 0, 0, 0);
    }

    // D mapping: col = l16, row = kq*4 + r.
    __shared__ float Ps[16][65];         // stride 65 -> conflict-free scatter
    if (kz == 1) {
#pragma unroll
        for (int r = 0; r < 4; ++r) {
            Ps[kq * 4 + r][wn + l16]      = acc0[r];
            Ps[kq * 4 + r][wn + 16 + l16] = acc1[r];
        }
    }
    __syncthreads();
    if (kz == 0) {
        float* p0 = P + (size_t)mBase * 1024 + cBase + wn;
#pragma unroll
        for (int r = 0; r < 4; ++r) {
            const int row = kq * 4 + r;
            p0[(size_t)row * 1024 + l16]      = acc0[r] + Ps[row][wn + l16];
            p0[(size_t)row * 1024 + 16 + l16] = acc1[r] + Ps[row][wn + 16 + l16];
        }
    }
}

// ---------------- K3: broadcast-add streaming the output --------------------
__global__ __launch_bounds__(256) void bcast_add(
    const float* __restrict__ Pe,   // (1024, 1024)  [b*T+t][c]
    const float* __restrict__ Pd,   // (256, 1024)   [b*U+u][c]
    float* __restrict__ out)        // (1024, 64, 1024)
{
    const int bt    = blockIdx.x;        // b*256 + t
    const int b     = bt >> 8;
    const int uBase = blockIdx.y << 5;   // 0 or 32
    const int c     = threadIdx.x << 2;

    const float4 e = *(const float4*)&Pe[(size_t)bt * 1024 + c];
    const float* pd = &Pd[((size_t)b * 64 + uBase) * 1024 + c];
    float*       po = &out[((size_t)bt * 64 + uBase) * 1024 + c];

#pragma unroll 4
    for (int u = 0; u < 32; ++u) {
        float4 d = *(const float4*)&pd[(size_t)u * 1024];
        v4f r = {e.x + d.x, e.y + d.y, e.z + d.z, e.w + d.w};
        __builtin_nontemporal_store(r, (v4f*)&po[(size_t)u * 1024]);
    }
}

extern "C" void kernel_launch(void* const* d_in, const int* in_sizes, int n_in,
                              void* d_out, int out_size, void* d_ws, size_t ws_size,
                              hipStream_t stream) {
    const float* enc = (const float*)d_in[0];   // (4,256,512)
    const float* dec = (const float*)d_in[1];   // (4,64,512)
    const float* W   = (const float*)d_in[2];   // (1024,1024)
    float* out = (float*)d_out;

    // Workspace layout (bytes): Pe 4 MiB | Pd 1 MiB | enc_bf 1 MiB |
    //                           dec_bf 256 KiB | W_bf 2 MiB   (= 8.25 MiB)
    char* ws = (char*)d_ws;
    float*  Pe     = (float*)(ws);
    float*  Pd     = (float*)(ws + (4u << 20));
    ushort* enc_bf = (ushort*)(ws + (5u << 20));
    ushort* dec_bf = (ushort*)(ws + (6u << 20));
    ushort* W_bf   = (ushort*)(ws + (6u << 20) + (1u << 18));

    cvt_fp32_bf16<<<dim3(1664), 256, 0, stream>>>(enc, dec, W, enc_bf, dec_bf, W_bf);
    proj_gemm_bf16<<<dim3(16, 80), 256, 0, stream>>>(enc_bf, dec_bf, W_bf, Pe, Pd);
    bcast_add<<<dim3(1024, 2), 256, 0, stream>>>(Pe, Pd, out);
}

// Round 6
// 71.618 us; speedup vs baseline: 1.6180x; 1.0416x over previous
//
#include <hip/hip_runtime.h>
#include <hip/hip_bf16.h>

// out[b,t,u,c] = enc[b,t,:]·W[c,:512] + dec[b,u,:]·W[c,512:]
// B=4, T=256, U=64, D=512, C=1024. Output 256 MiB fp32 (write floor ~40us).
//
// K1 cvt:   fp32 -> bf16 (enc/dec/W) once.
// K2 dec:   bf16-MFMA dec projection -> Pd (256x1024), computed exactly once.
// K3 fused: per block (16 bt x 64 c): split-K enc MFMA tile -> LDS, stage Pd
//           chunk -> LDS, then stream 256 KiB of output with nontemporal
//           float4 stores (no global loads in the stream loop). The enc GEMM
//           of later blocks hides under the write phase of earlier blocks.

typedef float v4f   __attribute__((ext_vector_type(4)));
typedef float f32x4 __attribute__((ext_vector_type(4)));
typedef __attribute__((ext_vector_type(8))) short short8;
typedef __attribute__((ext_vector_type(4))) short short4v;

__device__ inline short bf16_of(float f) {
    __hip_bfloat16 h = __float2bfloat16(f);   // RNE
    return *reinterpret_cast<short*>(&h);
}

// ---------------- K1: fp32 -> bf16 conversion --------------------------------
// float4 units: enc 131072, dec 32768, W 262144  (total 425984; grid 1664).
__global__ __launch_bounds__(256) void cvt_fp32_bf16(
    const float* __restrict__ enc, const float* __restrict__ dec,
    const float* __restrict__ W,
    ushort* __restrict__ enc_bf, ushort* __restrict__ dec_bf,
    ushort* __restrict__ W_bf)
{
    const int N1 = 131072, N2 = 32768;
    int i = blockIdx.x * 256 + threadIdx.x;
    const float* src; ushort* dst; int j;
    if (i < N1)           { src = enc; dst = enc_bf; j = i; }
    else if (i < N1 + N2) { src = dec; dst = dec_bf; j = i - N1; }
    else                  { src = W;   dst = W_bf;   j = i - N1 - N2; }
    float4 v = *(const float4*)&src[(size_t)j * 4];
    short4v o;
    o[0] = bf16_of(v.x); o[1] = bf16_of(v.y);
    o[2] = bf16_of(v.z); o[3] = bf16_of(v.w);
    *(short4v*)&dst[(size_t)j * 4] = o;
}

// ---------------- K2: dec projection GEMM (split-K, R5-proven) ---------------
// Grid (16 c-tiles, 16 m-tiles); block tile = 16(m) x 64(c).
__global__ __launch_bounds__(256) void dec_gemm_bf16(
    const ushort* __restrict__ Xd,  // (256, 512)  bf16
    const ushort* __restrict__ W,   // (1024, 1024) bf16; dec cols [512,1024)
    float* __restrict__ Pd)         // (256, 1024)
{
    const int tid  = threadIdx.x;
    const int wave = tid >> 6;
    const int lane = tid & 63;
    const int l16  = lane & 15;
    const int kq   = lane >> 4;

    const int kz = wave >> 1;
    const int wn = (wave & 1) * 32;
    const int mBase = blockIdx.y * 16;
    const int cBase = blockIdx.x * 64;

    const ushort* xr  = Xd + (size_t)(mBase + l16) * 512 + kz * 256;
    const ushort* wr0 = W + (size_t)(cBase + wn + l16) * 1024 + 512 + kz * 256;
    const ushort* wr1 = wr0 + (size_t)16 * 1024;

    f32x4 acc0 = {0.f,0.f,0.f,0.f}, acc1 = {0.f,0.f,0.f,0.f};
#pragma unroll 4
    for (int kb = 0; kb < 256; kb += 32) {
        const int k = kb + kq * 8;
        short8 a  = *(const short8*)&xr[k];
        short8 b0 = *(const short8*)&wr0[k];
        short8 b1 = *(const short8*)&wr1[k];
        acc0 = __builtin_amdgcn_mfma_f32_16x16x32_bf16(a, b0, acc0, 0, 0, 0);
        acc1 = __builtin_amdgcn_mfma_f32_16x16x32_bf16(a, b1, acc1, 0, 0, 0);
    }

    __shared__ float Ps[16][65];
    if (kz == 1) {
#pragma unroll
        for (int r = 0; r < 4; ++r) {
            Ps[kq * 4 + r][wn + l16]      = acc0[r];
            Ps[kq * 4 + r][wn + 16 + l16] = acc1[r];
        }
    }
    __syncthreads();
    if (kz == 0) {
        float* p0 = Pd + (size_t)mBase * 1024 + cBase + wn;
#pragma unroll
        for (int r = 0; r < 4; ++r) {
            const int row = kq * 4 + r;
            p0[(size_t)row * 1024 + l16]      = acc0[r] + Ps[row][wn + l16];
            p0[(size_t)row * 1024 + 16 + l16] = acc1[r] + Ps[row][wn + 16 + l16];
        }
    }
}

// ---------------- K3: fused enc GEMM + broadcast-add stream ------------------
// Grid (16 c-tiles, 64 bt-tiles), 256 threads = 4 waves.
// Wave w: kz = w>>1 (K half), wn = (w&1)*32 (c half).
__global__ __launch_bounds__(256) void fused_enc_stream(
    const ushort* __restrict__ Xe,  // (1024, 512) bf16
    const ushort* __restrict__ W,   // (1024, 1024) bf16; enc cols [0,512)
    const float* __restrict__ Pd,   // (256, 1024)
    float* __restrict__ out)        // (1024, 64, 1024)
{
    const int tid  = threadIdx.x;
    const int wave = tid >> 6;
    const int lane = tid & 63;
    const int l16  = lane & 15;
    const int kq   = lane >> 4;

    const int kz = wave >> 1;
    const int wn = (wave & 1) * 32;
    const int btBase = blockIdx.y * 16;
    const int cBase  = blockIdx.x * 64;
    const int b      = blockIdx.y >> 4;     // 16 bt-tiles per batch

    __shared__ float encS[2][16][68];       // ~8.7 KiB (split-K partials)
    __shared__ float decS[64][64];          // 16 KiB (this block's Pd chunk)

    // Stage decS: 4096 floats = 4 float4 per thread (one-time, overlaps GEMM).
#pragma unroll
    for (int p = 0; p < 4; ++p) {
        int s    = tid + p * 256;           // float4 slot 0..1023
        int row  = s >> 4;
        int slot = s & 15;
        float4 v = *(const float4*)&Pd[(size_t)(b * 64 + row) * 1024 + cBase + slot * 4];
        *(float4*)&decS[row][slot * 4] = v;
    }

    // Enc GEMM: 16 x 64 tile, K split across wave pairs.
    {
        const ushort* xr  = Xe + (size_t)(btBase + l16) * 512 + kz * 256;
        const ushort* wr0 = W  + (size_t)(cBase + wn + l16) * 1024 + kz * 256;
        const ushort* wr1 = wr0 + (size_t)16 * 1024;
        f32x4 acc0 = {0.f,0.f,0.f,0.f}, acc1 = {0.f,0.f,0.f,0.f};
#pragma unroll 4
        for (int kb = 0; kb < 256; kb += 32) {
            const int k = kb + kq * 8;
            short8 a  = *(const short8*)&xr[k];
            short8 b0 = *(const short8*)&wr0[k];
            short8 b1 = *(const short8*)&wr1[k];
            acc0 = __builtin_amdgcn_mfma_f32_16x16x32_bf16(a, b0, acc0, 0, 0, 0);
            acc1 = __builtin_amdgcn_mfma_f32_16x16x32_bf16(a, b1, acc1, 0, 0, 0);
        }
#pragma unroll
        for (int r = 0; r < 4; ++r) {        // D: col=l16, row=kq*4+r
            encS[kz][kq * 4 + r][wn + l16]      = acc0[r];
            encS[kz][kq * 4 + r][wn + 16 + l16] = acc1[r];
        }
    }

    __syncthreads();

    // Stream: thread (row=tid>>4, slot=tid&15) writes out[btBase+row, u, cBase+slot*4].
    const int row  = tid >> 4;
    const int c4   = (tid & 15) * 4;

    const float4 e0 = *(const float4*)&encS[0][row][c4];
    const float4 e1 = *(const float4*)&encS[1][row][c4];
    const v4f e = {e0.x + e1.x, e0.y + e1.y, e0.z + e1.z, e0.w + e1.w};

    float* po = out + (size_t)(btBase + row) * 64 * 1024 + cBase + c4;

#pragma unroll 8
    for (int u = 0; u < 64; ++u) {
        float4 d = *(const float4*)&decS[u][c4];
        v4f r = {e.x + d.x, e.y + d.y, e.z + d.z, e.w + d.w};
        __builtin_nontemporal_store(r, (v4f*)&po[(size_t)u * 1024]);
    }
}

extern "C" void kernel_launch(void* const* d_in, const int* in_sizes, int n_in,
                              void* d_out, int out_size, void* d_ws, size_t ws_size,
                              hipStream_t stream) {
    const float* enc = (const float*)d_in[0];   // (4,256,512)
    const float* dec = (const float*)d_in[1];   // (4,64,512)
    const float* W   = (const float*)d_in[2];   // (1024,1024)
    float* out = (float*)d_out;

    // Workspace: Pd 1 MiB | enc_bf 1 MiB | dec_bf 256 KiB | W_bf 2 MiB (4.25 MiB)
    char* ws = (char*)d_ws;
    float*  Pd     = (float*)(ws);
    ushort* enc_bf = (ushort*)(ws + (1u << 20));
    ushort* dec_bf = (ushort*)(ws + (2u << 20));
    ushort* W_bf   = (ushort*)(ws + (2u << 20) + (1u << 18));

    cvt_fp32_bf16<<<dim3(1664), 256, 0, stream>>>(enc, dec, W, enc_bf, dec_bf, W_bf);
    dec_gemm_bf16<<<dim3(16, 16), 256, 0, stream>>>(dec_bf, W_bf, Pd);
    fused_enc_stream<<<dim3(16, 64), 256, 0, stream>>>(enc_bf, W_bf, Pd, out);
}

// Round 7
// 64.226 us; speedup vs baseline: 1.8042x; 1.1151x over previous
//
#include <hip/hip_runtime.h>
#include <hip/hip_bf16.h>

// out[b,t,u,c] = enc[b,t,:]·W[c,:512] + dec[b,u,:]·W[c,512:]
// B=4, T=256, U=64, D=512, C=1024. Output 256 MiB fp32 (write floor ~40us).
//
// K1 cvt:   fp32 -> bf16 AND permute into MFMA-fragment order: for each
//           16-row x 32-k block, lane (kq,l16)'s 8 k-values (16 B) stored at
//           block*1024 + lane*16. GEMM loads become coalesced 1 KB wave-loads
//           (fixes the 64-scattered-16B-txn bottleneck of direct frag loads).
// K2 dec:   bf16-MFMA dec projection -> Pd (256x1024), fragment loads.
// K3 fused: per block (16 bt x 64 c): enc MFMA tile (frag loads) -> LDS,
//           stage Pd chunk -> LDS, stream 256 KiB with nontemporal float4.

typedef float v4f   __attribute__((ext_vector_type(4)));
typedef float f32x4 __attribute__((ext_vector_type(4)));
typedef __attribute__((ext_vector_type(8))) short short8;

__device__ inline short bf16_of(float f) {
    __hip_bfloat16 h = __float2bfloat16(f);   // RNE
    return *reinterpret_cast<short*>(&h);
}

// ---------------- K1: fp32 -> bf16 fragment-layout permute -------------------
// One wave per 16x32 fragment block (1 KiB out). Wave-task ids:
//   [0,1024)    : enc  (64 mb x 16 kb)
//   [1024,1280) : dec  (16 mb x 16 kb)
//   [1280,2304) : Wenc (64 cb x 16 kb), W cols [0,512)
//   [2304,3328) : Wdec (64 cb x 16 kb), W cols [512,1024)
// Grid: 832 blocks x 256 threads (4 waves). Lane (kq,l16) reads 8 fp32 from
// src[row0+l16][k0+kq*8..+8], converts, stores 16 B at blk*1024 + lane*16.
__global__ __launch_bounds__(256) void cvt_frag(
    const float* __restrict__ enc, const float* __restrict__ dec,
    const float* __restrict__ W,
    ushort* __restrict__ Xe_f, ushort* __restrict__ Xd_f,
    ushort* __restrict__ We_f, ushort* __restrict__ Wd_f)
{
    const int tid  = threadIdx.x;
    const int lane = tid & 63;
    const int l16  = lane & 15;
    const int kq   = lane >> 4;
    const int gid  = blockIdx.x * 4 + (tid >> 6);

    const float* src; ushort* dst; int g, rowStride, colOfs;
    if (gid < 1024)      { src = enc; dst = Xe_f; g = gid;        rowStride = 512;  colOfs = 0;   }
    else if (gid < 1280) { src = dec; dst = Xd_f; g = gid - 1024; rowStride = 512;  colOfs = 0;   }
    else if (gid < 2304) { src = W;   dst = We_f; g = gid - 1280; rowStride = 1024; colOfs = 0;   }
    else                 { src = W;   dst = Wd_f; g = gid - 2304; rowStride = 1024; colOfs = 512; }

    const int rb  = g >> 4;       // 16-row block
    const int kbi = g & 15;       // 32-k block
    const float* p = src + (size_t)(rb * 16 + l16) * rowStride + colOfs + kbi * 32 + kq * 8;
    float4 lo = *(const float4*)p;
    float4 hi = *(const float4*)(p + 4);
    short8 o;
    o[0] = bf16_of(lo.x); o[1] = bf16_of(lo.y); o[2] = bf16_of(lo.z); o[3] = bf16_of(lo.w);
    o[4] = bf16_of(hi.x); o[5] = bf16_of(hi.y); o[6] = bf16_of(hi.z); o[7] = bf16_of(hi.w);
    *(short8*)&dst[(size_t)g * 512 + lane * 8] = o;
}

// ---------------- K2: dec projection GEMM (fragment loads, split-K) ----------
// Grid (16 c-tiles, 16 m-tiles); block tile = 16(m) x 64(c); 4 waves.
__global__ __launch_bounds__(256) void dec_gemm_bf16(
    const ushort* __restrict__ Xd_f,  // frag layout (16 mb x 16 kb)
    const ushort* __restrict__ Wd_f,  // frag layout (64 cb x 16 kb)
    float* __restrict__ Pd)           // (256, 1024)
{
    const int tid  = threadIdx.x;
    const int wave = tid >> 6;
    const int lane = tid & 63;
    const int l16  = lane & 15;
    const int kq   = lane >> 4;

    const int kz = wave >> 1;          // K half: kb blocks kz*8 .. kz*8+8
    const int wn = (wave & 1) * 32;
    const int mb = blockIdx.y;
    const int cBase = blockIdx.x * 64;
    const int cb0 = blockIdx.x * 4 + (wave & 1) * 2;

    const short8* xa = (const short8*)Xd_f + (size_t)(mb  * 16 + kz * 8) * 64 + lane;
    const short8* wb0 = (const short8*)Wd_f + (size_t)(cb0       * 16 + kz * 8) * 64 + lane;
    const short8* wb1 = (const short8*)Wd_f + (size_t)((cb0 + 1) * 16 + kz * 8) * 64 + lane;

    f32x4 acc0 = {0.f,0.f,0.f,0.f}, acc1 = {0.f,0.f,0.f,0.f};
#pragma unroll
    for (int s = 0; s < 8; ++s) {
        short8 a  = xa [(size_t)s * 64];
        short8 b0 = wb0[(size_t)s * 64];
        short8 b1 = wb1[(size_t)s * 64];
        acc0 = __builtin_amdgcn_mfma_f32_16x16x32_bf16(a, b0, acc0, 0, 0, 0);
        acc1 = __builtin_amdgcn_mfma_f32_16x16x32_bf16(a, b1, acc1, 0, 0, 0);
    }

    __shared__ float Ps[16][65];
    if (kz == 1) {
#pragma unroll
        for (int r = 0; r < 4; ++r) {
            Ps[kq * 4 + r][wn + l16]      = acc0[r];
            Ps[kq * 4 + r][wn + 16 + l16] = acc1[r];
        }
    }
    __syncthreads();
    if (kz == 0) {
        float* p0 = Pd + (size_t)(mb * 16) * 1024 + cBase + wn;
#pragma unroll
        for (int r = 0; r < 4; ++r) {
            const int row = kq * 4 + r;
            p0[(size_t)row * 1024 + l16]      = acc0[r] + Ps[row][wn + l16];
            p0[(size_t)row * 1024 + 16 + l16] = acc1[r] + Ps[row][wn + 16 + l16];
        }
    }
}

// ---------------- K3: fused enc GEMM + broadcast-add stream ------------------
// Grid (16 c-tiles, 64 bt-tiles), 256 threads = 4 waves.
__global__ __launch_bounds__(256) void fused_enc_stream(
    const ushort* __restrict__ Xe_f,  // frag layout (64 mb x 16 kb)
    const ushort* __restrict__ We_f,  // frag layout (64 cb x 16 kb)
    const float* __restrict__ Pd,     // (256, 1024)
    float* __restrict__ out)          // (1024, 64, 1024)
{
    const int tid  = threadIdx.x;
    const int wave = tid >> 6;
    const int lane = tid & 63;
    const int l16  = lane & 15;
    const int kq   = lane >> 4;

    const int kz = wave >> 1;
    const int wn = (wave & 1) * 32;
    const int btBase = blockIdx.y * 16;
    const int cBase  = blockIdx.x * 64;
    const int b      = blockIdx.y >> 4;
    const int cb0    = blockIdx.x * 4 + (wave & 1) * 2;

    __shared__ float encS[2][16][68];       // split-K partials
    __shared__ float decS[64][64];          // this block's Pd chunk

    // Stage decS: 4096 floats = 4 float4 per thread.
#pragma unroll
    for (int p = 0; p < 4; ++p) {
        int s    = tid + p * 256;
        int row  = s >> 4;
        int slot = s & 15;
        float4 v = *(const float4*)&Pd[(size_t)(b * 64 + row) * 1024 + cBase + slot * 4];
        *(float4*)&decS[row][slot * 4] = v;
    }

    // Enc GEMM: 16 x 64 tile, fragment loads, K split across wave pairs.
    {
        const short8* xa  = (const short8*)Xe_f + (size_t)(blockIdx.y * 16 + kz * 8) * 64 + lane;
        const short8* wb0 = (const short8*)We_f + (size_t)(cb0       * 16 + kz * 8) * 64 + lane;
        const short8* wb1 = (const short8*)We_f + (size_t)((cb0 + 1) * 16 + kz * 8) * 64 + lane;
        f32x4 acc0 = {0.f,0.f,0.f,0.f}, acc1 = {0.f,0.f,0.f,0.f};
#pragma unroll
        for (int s = 0; s < 8; ++s) {
            short8 a  = xa [(size_t)s * 64];
            short8 b0 = wb0[(size_t)s * 64];
            short8 b1 = wb1[(size_t)s * 64];
            acc0 = __builtin_amdgcn_mfma_f32_16x16x32_bf16(a, b0, acc0, 0, 0, 0);
            acc1 = __builtin_amdgcn_mfma_f32_16x16x32_bf16(a, b1, acc1, 0, 0, 0);
        }
#pragma unroll
        for (int r = 0; r < 4; ++r) {        // D: col=l16, row=kq*4+r
            encS[kz][kq * 4 + r][wn + l16]      = acc0[r];
            encS[kz][kq * 4 + r][wn + 16 + l16] = acc1[r];
        }
    }

    __syncthreads();

    // Stream: thread (row=tid>>4, slot=tid&15) -> out[btBase+row, u, cBase+slot*4].
    const int row = tid >> 4;
    const int c4  = (tid & 15) * 4;

    const float4 e0 = *(const float4*)&encS[0][row][c4];
    const float4 e1 = *(const float4*)&encS[1][row][c4];
    const v4f e = {e0.x + e1.x, e0.y + e1.y, e0.z + e1.z, e0.w + e1.w};

    float* po = out + (size_t)(btBase + row) * 64 * 1024 + cBase + c4;

#pragma unroll 8
    for (int u = 0; u < 64; ++u) {
        float4 d = *(const float4*)&decS[u][c4];
        v4f r = {e.x + d.x, e.y + d.y, e.z + d.z, e.w + d.w};
        __builtin_nontemporal_store(r, (v4f*)&po[(size_t)u * 1024]);
    }
}

extern "C" void kernel_launch(void* const* d_in, const int* in_sizes, int n_in,
                              void* d_out, int out_size, void* d_ws, size_t ws_size,
                              hipStream_t stream) {
    const float* enc = (const float*)d_in[0];   // (4,256,512)
    const float* dec = (const float*)d_in[1];   // (4,64,512)
    const float* W   = (const float*)d_in[2];   // (1024,1024)
    float* out = (float*)d_out;

    // Workspace: Pd 1 MiB | Xe_f 1 MiB | Xd_f 256 KiB | We_f 1 MiB | Wd_f 1 MiB
    char* ws = (char*)d_ws;
    float*  Pd   = (float*)(ws);
    ushort* Xe_f = (ushort*)(ws + (1u << 20));
    ushort* Xd_f = (ushort*)(ws + (2u << 20));
    ushort* We_f = (ushort*)(ws + (2u << 20) + (1u << 18));
    ushort* Wd_f = (ushort*)(ws + (3u << 20) + (1u << 18));

    cvt_frag<<<dim3(832), 256, 0, stream>>>(enc, dec, W, Xe_f, Xd_f, We_f, Wd_f);
    dec_gemm_bf16<<<dim3(16, 16), 256, 0, stream>>>(Xd_f, Wd_f, Pd);
    fused_enc_stream<<<dim3(16, 64), 256, 0, stream>>>(Xe_f, We_f, Pd, out);
}